// Round 8
// baseline (918.965 us; speedup 1.0000x reference)
//
#include <hip/hip_runtime.h>
#include <hip/hip_bf16.h>

// ---------------------------------------------------------------------------
// RobustGNN: 5x GCNConv(relu) -> segment_max pool -> linear
// N=100000, E=1600000, F_IN=14, H=64, C=2, G=512
//
// R8 changes vs R7 (focus: layer structure):
//  - Per-layer fusion via A_hat(hW) = (A_hat h)W: one kernel per layer does
//    CSR gather (lane=feature) + in-register GEMM epilogue (64x shfl
//    broadcast against W column in VGPRs) + bias + relu + ds pre-scale.
//    Eliminates buf_m round-trip (2 x 25.6MB/layer) and 5 launches.
//  - Layer 1 fused the same way through a per-wave LDS slot (16-dim).
//  - count_edges -> count_sharded (4096 blocks, XCD-pinned like fill):
//    deg atomics stay XCD-local.
//  - Kept: R4 fill_csr_sharded (measured best), pool_linear fusion.
// ---------------------------------------------------------------------------

#define HDIM 64
#define SCAN_CHUNK 1024
#define FILL_S 8

// ---------------- preprocessing ----------------

// Sharded degree count: shard = blockIdx & 7 pins each dst-range's atomics
// to ~one XCD's L2 (dst re-read x8 is L3-resident, cheap).
__global__ __launch_bounds__(256) void count_sharded(const int* __restrict__ dst,
                                                     int* __restrict__ deg,
                                                     int E, int shard_w, int nchunks) {
    int shard = blockIdx.x & (FILL_S - 1);
    int chunk = blockIdx.x >> 3;
    int epc = (E + nchunks - 1) / nchunks;
    int e0 = chunk * epc;
    int e1 = min(e0 + epc, E);
    int lo = shard * shard_w, hi = lo + shard_w;
    for (int e = e0 + (int)threadIdx.x; e < e1; e += 256) {
        int d = dst[e];
        if (d >= lo && d < hi) atomicAdd(&deg[d], 1);
    }
}

__global__ __launch_bounds__(256) void partial_sums(const int* __restrict__ deg,
                                                    int* __restrict__ psum, int n) {
    __shared__ int red[256];
    int base = blockIdx.x * SCAN_CHUNK;
    int s = 0;
    #pragma unroll
    for (int j = 0; j < 4; ++j) {
        int i = base + j * 256 + threadIdx.x;
        if (i < n) s += deg[i];
    }
    red[threadIdx.x] = s;
    __syncthreads();
    for (int off = 128; off > 0; off >>= 1) {
        if (threadIdx.x < off) red[threadIdx.x] += red[threadIdx.x + off];
        __syncthreads();
    }
    if (threadIdx.x == 0) psum[blockIdx.x] = red[0];
}

__global__ __launch_bounds__(128) void scan_partials(int* __restrict__ psum, int nb) {
    __shared__ int tmp[128];
    int t = threadIdx.x;
    int v = (t < nb) ? psum[t] : 0;
    tmp[t] = v;
    __syncthreads();
    for (int off = 1; off < 128; off <<= 1) {
        int u = (t >= off) ? tmp[t - off] : 0;
        __syncthreads();
        tmp[t] += u;
        __syncthreads();
    }
    if (t < nb) psum[t] = tmp[t] - v;  // exclusive
}

__global__ __launch_bounds__(256) void scan_final(const int* __restrict__ deg,
                                                  const int* __restrict__ psum,
                                                  int* __restrict__ rowptr, int n) {
    __shared__ int ts[256];
    int t = threadIdx.x;
    int base = blockIdx.x * SCAN_CHUNK + t * 4;
    int v[4];
    int s = 0;
    #pragma unroll
    for (int j = 0; j < 4; ++j) {
        int i = base + j;
        v[j] = (i < n) ? deg[i] : 0;
        s += v[j];
    }
    ts[t] = s;
    __syncthreads();
    int mine = s;
    for (int off = 1; off < 256; off <<= 1) {
        int u = (t >= off) ? ts[t - off] : 0;
        __syncthreads();
        ts[t] += u;
        __syncthreads();
    }
    int ex = ts[t] - mine + psum[blockIdx.x];
    #pragma unroll
    for (int j = 0; j < 4; ++j) {
        int i = base + j;
        if (i < n) rowptr[i] = ex;
        ex += v[j];
    }
}

__global__ __launch_bounds__(256) void node_arrays(const int* __restrict__ deg,
                                                   const int* __restrict__ rowptr,
                                                   float* __restrict__ ds,
                                                   int* __restrict__ cursor, int n) {
    int i = blockIdx.x * blockDim.x + threadIdx.x;
    if (i < n) {
        float d = (float)(deg[i] + 1);  // +1 self loop
        ds[i] = 1.0f / sqrtf(d);
        cursor[i] = rowptr[i];
    }
}

// Sharded CSR fill (R4 measured-best).
__global__ __launch_bounds__(256) void fill_csr_sharded(const int* __restrict__ src,
                                                        const int* __restrict__ dst,
                                                        int* __restrict__ cursor,
                                                        int* __restrict__ csr_src,
                                                        int E, int shard_w, int nchunks) {
    int shard = blockIdx.x & (FILL_S - 1);
    int chunk = blockIdx.x >> 3;
    int epc = (E + nchunks - 1) / nchunks;
    int e0 = chunk * epc;
    int e1 = min(e0 + epc, E);
    int lo = shard * shard_w, hi = lo + shard_w;
    for (int e = e0 + (int)threadIdx.x; e < e1; e += 256) {
        int d = dst[e];
        if (d >= lo && d < hi) {
            int pos = atomicAdd(&cursor[d], 1);
            csr_src[pos] = src[e];
        }
    }
}

// xp[n][16] = (j<14 ? x[n][j] : 0) * ds[n]
__global__ __launch_bounds__(256) void pad_scale_x(const float* __restrict__ x,
                                                   const float* __restrict__ ds,
                                                   float* __restrict__ xp, int n_nodes) {
    int idx = blockIdx.x * blockDim.x + threadIdx.x;
    if (idx >= n_nodes * 16) return;
    int n = idx >> 4, j = idx & 15;
    xp[idx] = (j < 14) ? x[n * 14 + j] * ds[n] : 0.0f;
}

// ---------------- layer 1 fused: h1' = ds*relu((A_hat x)@W1 + b1) ----------------
// Wave handles 4 nodes (16 lanes each) for the gather; per-wave LDS slot
// holds the 4x16 aggregate; epilogue: each lane = output feature.

__global__ __launch_bounds__(256) void gather16_fused(const float* __restrict__ xp,
                                                      const int* __restrict__ rowptr,
                                                      const int* __restrict__ cnt,
                                                      const int* __restrict__ csr_src,
                                                      const float* __restrict__ ds,
                                                      const float* __restrict__ W1,
                                                      const float* __restrict__ b1,
                                                      float* __restrict__ hout, int n_nodes) {
    __shared__ float lds[256];  // 4 waves x 64
    int lane = threadIdx.x & 63;
    int sub = lane >> 4, l = lane & 15;
    int wave_in = threadIdx.x >> 6;
    int wave = blockIdx.x * 4 + wave_in;
    int node = wave * 4 + sub;

    float wcol16[16];
    #pragma unroll
    for (int k = 0; k < 16; ++k) wcol16[k] = (k < 14) ? W1[k * HDIM + lane] : 0.f;
    float bl = b1[lane];

    float a = 0.f;
    if (node < n_nodes) {
        float dsn = ds[node];
        float a0 = xp[node * 16 + l];  // self
        float a1 = 0.f, a2 = 0.f, a3 = 0.f;
        int s = rowptr[node];
        int e = s + cnt[node];
        int i = s;
        for (; i + 3 < e; i += 4) {
            int s0 = csr_src[i], s1 = csr_src[i + 1], s2 = csr_src[i + 2], s3 = csr_src[i + 3];
            a0 += xp[s0 * 16 + l];
            a1 += xp[s1 * 16 + l];
            a2 += xp[s2 * 16 + l];
            a3 += xp[s3 * 16 + l];
        }
        for (; i < e; ++i) a0 += xp[csr_src[i] * 16 + l];
        a = ((a0 + a1) + (a2 + a3)) * dsn;
    }
    lds[wave_in * 64 + lane] = a;  // same-wave write->read: in-order, no barrier

    #pragma unroll
    for (int nd = 0; nd < 4; ++nd) {
        int n2 = wave * 4 + nd;
        if (n2 >= n_nodes) break;
        const float* av = &lds[wave_in * 64 + nd * 16];
        float o0 = bl, o1 = 0.f, o2 = 0.f, o3 = 0.f;
        #pragma unroll
        for (int k4 = 0; k4 < 4; ++k4) {
            o0 += av[4 * k4 + 0] * wcol16[4 * k4 + 0];
            o1 += av[4 * k4 + 1] * wcol16[4 * k4 + 1];
            o2 += av[4 * k4 + 2] * wcol16[4 * k4 + 2];
            o3 += av[4 * k4 + 3] * wcol16[4 * k4 + 3];
        }
        float o = fmaxf((o0 + o1) + (o2 + o3), 0.f) * ds[n2];
        hout[(size_t)n2 * HDIM + lane] = o;
    }
}

// ---------------- layers 2-5 fused: gather + GEMM + bias + relu (+ds) ----------------
// One wave per node; lane = feature. Epilogue: o = relu(a.W + b) with a
// broadcast via shfl (v_readlane) and W column in VGPRs.

template <bool SCALE_OUT>
__global__ __launch_bounds__(256) void gcn_fused(const float* __restrict__ m,
                                                 const int* __restrict__ rowptr,
                                                 const int* __restrict__ cnt,
                                                 const int* __restrict__ csr_src,
                                                 const float* __restrict__ ds,
                                                 const float* __restrict__ W,
                                                 const float* __restrict__ bias,
                                                 float* __restrict__ hout, int n_nodes) {
    int lane = threadIdx.x & 63;
    int node = blockIdx.x * (blockDim.x >> 6) + (threadIdx.x >> 6);
    if (node >= n_nodes) return;
    float wcol[64];
    #pragma unroll
    for (int k = 0; k < 64; ++k) wcol[k] = W[k * HDIM + lane];
    float dsn = ds[node];

    float a0 = m[(size_t)node * HDIM + lane];  // self (input pre-scaled by ds)
    float a1 = 0.f, a2 = 0.f, a3 = 0.f;
    float a4 = 0.f, a5 = 0.f, a6 = 0.f, a7 = 0.f;
    int s = rowptr[node];
    int e = s + cnt[node];
    int i = s;
    for (; i + 15 < e; i += 16) {
        int t0 = csr_src[i],      t1 = csr_src[i + 1],  t2 = csr_src[i + 2],  t3 = csr_src[i + 3];
        int t4 = csr_src[i + 4],  t5 = csr_src[i + 5],  t6 = csr_src[i + 6],  t7 = csr_src[i + 7];
        int t8 = csr_src[i + 8],  t9 = csr_src[i + 9],  ta = csr_src[i + 10], tb = csr_src[i + 11];
        int tc = csr_src[i + 12], td = csr_src[i + 13], te = csr_src[i + 14], tf = csr_src[i + 15];
        a0 += m[(size_t)t0 * HDIM + lane];
        a1 += m[(size_t)t1 * HDIM + lane];
        a2 += m[(size_t)t2 * HDIM + lane];
        a3 += m[(size_t)t3 * HDIM + lane];
        a4 += m[(size_t)t4 * HDIM + lane];
        a5 += m[(size_t)t5 * HDIM + lane];
        a6 += m[(size_t)t6 * HDIM + lane];
        a7 += m[(size_t)t7 * HDIM + lane];
        a0 += m[(size_t)t8 * HDIM + lane];
        a1 += m[(size_t)t9 * HDIM + lane];
        a2 += m[(size_t)ta * HDIM + lane];
        a3 += m[(size_t)tb * HDIM + lane];
        a4 += m[(size_t)tc * HDIM + lane];
        a5 += m[(size_t)td * HDIM + lane];
        a6 += m[(size_t)te * HDIM + lane];
        a7 += m[(size_t)tf * HDIM + lane];
    }
    for (; i + 7 < e; i += 8) {
        int t0 = csr_src[i],     t1 = csr_src[i + 1], t2 = csr_src[i + 2], t3 = csr_src[i + 3];
        int t4 = csr_src[i + 4], t5 = csr_src[i + 5], t6 = csr_src[i + 6], t7 = csr_src[i + 7];
        a0 += m[(size_t)t0 * HDIM + lane];
        a1 += m[(size_t)t1 * HDIM + lane];
        a2 += m[(size_t)t2 * HDIM + lane];
        a3 += m[(size_t)t3 * HDIM + lane];
        a4 += m[(size_t)t4 * HDIM + lane];
        a5 += m[(size_t)t5 * HDIM + lane];
        a6 += m[(size_t)t6 * HDIM + lane];
        a7 += m[(size_t)t7 * HDIM + lane];
    }
    for (; i + 1 < e; i += 2) {
        int t0 = csr_src[i], t1 = csr_src[i + 1];
        a0 += m[(size_t)t0 * HDIM + lane];
        a1 += m[(size_t)t1 * HDIM + lane];
    }
    if (i < e) a0 += m[(size_t)csr_src[i] * HDIM + lane];
    float a = (((a0 + a1) + (a2 + a3)) + ((a4 + a5) + (a6 + a7))) * dsn;

    // epilogue: o[lane] = relu( sum_k a_k * W[k][lane] + b[lane] )
    float o0 = bias[lane], o1 = 0.f, o2 = 0.f, o3 = 0.f;
    #pragma unroll
    for (int k = 0; k < 16; ++k) {
        o0 += __shfl(a, 4 * k + 0) * wcol[4 * k + 0];
        o1 += __shfl(a, 4 * k + 1) * wcol[4 * k + 1];
        o2 += __shfl(a, 4 * k + 2) * wcol[4 * k + 2];
        o3 += __shfl(a, 4 * k + 3) * wcol[4 * k + 3];
    }
    float o = fmaxf((o0 + o1) + (o2 + o3), 0.f);
    if constexpr (SCALE_OUT) o *= dsn;
    hout[(size_t)node * HDIM + lane] = o;
}

// ---------------- fused pool (segment max) + linear head ----------------

__global__ __launch_bounds__(256) void pool_linear(const float* __restrict__ h,
                                                   const int* __restrict__ batch,
                                                   const float* __restrict__ Wlin,
                                                   const float* __restrict__ blin,
                                                   float* __restrict__ out,
                                                   int n_nodes, int n_graphs) {
    int lane = threadIdx.x & 63;
    int g = blockIdx.x * (blockDim.x >> 6) + (threadIdx.x >> 6);
    if (g >= n_graphs) return;
    int lo = 0, hi = n_nodes;
    while (lo < hi) { int mid = (lo + hi) >> 1; if (batch[mid] < g) lo = mid + 1; else hi = mid; }
    int start = lo;
    hi = n_nodes;
    while (lo < hi) { int mid = (lo + hi) >> 1; if (batch[mid] < g + 1) lo = mid + 1; else hi = mid; }
    int end = lo;
    float vmax = 0.f;  // h >= 0 post-relu
    for (int n = start; n < end; ++n) vmax = fmaxf(vmax, h[(size_t)n * HDIM + lane]);
    float p0 = vmax * Wlin[lane * 2 + 0];
    float p1 = vmax * Wlin[lane * 2 + 1];
    #pragma unroll
    for (int off = 32; off > 0; off >>= 1) {
        p0 += __shfl_xor(p0, off);
        p1 += __shfl_xor(p1, off);
    }
    if (lane == 0) {
        out[g * 2 + 0] = p0 + blin[0];
        out[g * 2 + 1] = p1 + blin[1];
    }
}

// ---------------- launch ----------------

extern "C" void kernel_launch(void* const* d_in, const int* in_sizes, int n_in,
                              void* d_out, int out_size, void* d_ws, size_t ws_size,
                              hipStream_t stream) {
    const float* x    = (const float*)d_in[0];
    const float* W1   = (const float*)d_in[1];
    const float* b1   = (const float*)d_in[2];
    const float* W2   = (const float*)d_in[3];
    const float* b2   = (const float*)d_in[4];
    const float* W3   = (const float*)d_in[5];
    const float* b3   = (const float*)d_in[6];
    const float* W4   = (const float*)d_in[7];
    const float* b4   = (const float*)d_in[8];
    const float* W5   = (const float*)d_in[9];
    const float* b5   = (const float*)d_in[10];
    const float* Wlin = (const float*)d_in[11];
    const float* blin = (const float*)d_in[12];
    const int* edge_index = (const int*)d_in[13];
    const int* batch      = (const int*)d_in[14];

    const int N = in_sizes[0] / 14;
    const int E = in_sizes[13] / 2;
    const int G = out_size / 2;
    const int* srcp = edge_index;
    const int* dstp = edge_index + E;

    char* ws = (char*)d_ws;
    size_t off = 0;
    auto alloc = [&](size_t bytes) -> void* {
        void* p = ws + off;
        off = (off + bytes + 255) & ~(size_t)255;
        return p;
    };
    int*   deg     = (int*)alloc((size_t)N * 4);
    int*   rowptr  = (int*)alloc((size_t)N * 4);
    int*   cursor  = (int*)alloc((size_t)N * 4);
    int*   psum    = (int*)alloc(128 * 4);
    float* ds      = (float*)alloc((size_t)N * 4);
    int*   csr_src = (int*)alloc((size_t)E * 4);
    float* bufA    = (float*)alloc((size_t)N * HDIM * 4);
    float* bufB    = (float*)alloc((size_t)N * HDIM * 4);
    (void)ws_size;
    float* xp = bufA;  // [N][16]; region reused by layer-2 output (dead by then)

    const int NB = (N + SCAN_CHUNK - 1) / SCAN_CHUNK;
    const int fill_chunks = 512;
    const int shard_w = (N + FILL_S - 1) / FILL_S;  // 12500

    hipMemsetAsync(deg, 0, (size_t)N * 4, stream);
    count_sharded<<<fill_chunks * FILL_S, 256, 0, stream>>>(dstp, deg, E, shard_w, fill_chunks);
    partial_sums<<<NB, 256, 0, stream>>>(deg, psum, N);
    scan_partials<<<1, 128, 0, stream>>>(psum, NB);
    scan_final<<<NB, 256, 0, stream>>>(deg, psum, rowptr, N);
    node_arrays<<<(N + 255) / 256, 256, 0, stream>>>(deg, rowptr, ds, cursor, N);
    pad_scale_x<<<(N * 16 + 255) / 256, 256, 0, stream>>>(x, ds, xp, N);
    fill_csr_sharded<<<fill_chunks * FILL_S, 256, 0, stream>>>(srcp, dstp, cursor, csr_src,
                                                               E, shard_w, fill_chunks);

    const int g16_blocks = (N + 15) / 16;      // 16 nodes/block
    const int fused_blocks = (N + 3) / 4;      // 1 node/wave, 4 waves/block

    // L1: xp(A) -> B ; L2: B -> A ; L3: A -> B ; L4: B -> A ; L5: A -> B
    gather16_fused<<<g16_blocks, 256, 0, stream>>>(xp, rowptr, deg, csr_src, ds, W1, b1, bufB, N);
    gcn_fused<true ><<<fused_blocks, 256, 0, stream>>>(bufB, rowptr, deg, csr_src, ds, W2, b2, bufA, N);
    gcn_fused<true ><<<fused_blocks, 256, 0, stream>>>(bufA, rowptr, deg, csr_src, ds, W3, b3, bufB, N);
    gcn_fused<true ><<<fused_blocks, 256, 0, stream>>>(bufB, rowptr, deg, csr_src, ds, W4, b4, bufA, N);
    gcn_fused<false><<<fused_blocks, 256, 0, stream>>>(bufA, rowptr, deg, csr_src, ds, W5, b5, bufB, N);

    pool_linear<<<(G + 3) / 4, 256, 0, stream>>>(bufB, batch, Wlin, blin, (float*)d_out, N, G);
}

// Round 10
// 704.288 us; speedup vs baseline: 1.3048x; 1.3048x over previous
//
#include <hip/hip_runtime.h>
#include <hip/hip_bf16.h>

// ---------------------------------------------------------------------------
// RobustGNN: 5x GCNConv(relu) -> segment_max pool -> linear
// N=100000, E=1600000, F_IN=14, H=64, C=2, G=512
//
// R10 changes vs R9 (recovery + numerics-exact experiments):
//  - REVERTED to R7's bit-proven numeric path: gather16 (unroll4),
//    gcn_gather (unroll16, sequential 8-acc association), L1 matmul
//    <16,14,true,false>. R9 failed at 1.95e-3 (= 2^-9): either the L1
//    double-scale flag or gather4's shfl-tree reassociation; both reverted.
//    Lesson: summation association is part of the contract here.
//  - count_sharded (R8-passed) replaces count_edges: XCD-local deg atomics.
//  - matmul_k: LDS-staged rows. One coalesced 1KB load/wave (lane=float4)
//    + identical FMA loop reading LDS broadcasts. Bit-identical math;
//    replaces 64 broadcast global loads per wave-iter.
// ---------------------------------------------------------------------------

#define HDIM 64
#define SCAN_CHUNK 1024
#define FILL_S 8

// ---------------- preprocessing ----------------

// Sharded degree count (R8): shard = blockIdx & 7 pins each dst-range's
// atomics to ~one XCD's L2 (dst re-read x8 is cheap).
__global__ __launch_bounds__(256) void count_sharded(const int* __restrict__ dst,
                                                     int* __restrict__ deg,
                                                     int E, int shard_w, int nchunks) {
    int shard = blockIdx.x & (FILL_S - 1);
    int chunk = blockIdx.x >> 3;
    int epc = (E + nchunks - 1) / nchunks;
    int e0 = chunk * epc;
    int e1 = min(e0 + epc, E);
    int lo = shard * shard_w, hi = lo + shard_w;
    for (int e = e0 + (int)threadIdx.x; e < e1; e += 256) {
        int d = dst[e];
        if (d >= lo && d < hi) atomicAdd(&deg[d], 1);
    }
}

__global__ __launch_bounds__(256) void partial_sums(const int* __restrict__ deg,
                                                    int* __restrict__ psum, int n) {
    __shared__ int red[256];
    int base = blockIdx.x * SCAN_CHUNK;
    int s = 0;
    #pragma unroll
    for (int j = 0; j < 4; ++j) {
        int i = base + j * 256 + threadIdx.x;
        if (i < n) s += deg[i];
    }
    red[threadIdx.x] = s;
    __syncthreads();
    for (int off = 128; off > 0; off >>= 1) {
        if (threadIdx.x < off) red[threadIdx.x] += red[threadIdx.x + off];
        __syncthreads();
    }
    if (threadIdx.x == 0) psum[blockIdx.x] = red[0];
}

__global__ __launch_bounds__(128) void scan_partials(int* __restrict__ psum, int nb) {
    __shared__ int tmp[128];
    int t = threadIdx.x;
    int v = (t < nb) ? psum[t] : 0;
    tmp[t] = v;
    __syncthreads();
    for (int off = 1; off < 128; off <<= 1) {
        int u = (t >= off) ? tmp[t - off] : 0;
        __syncthreads();
        tmp[t] += u;
        __syncthreads();
    }
    if (t < nb) psum[t] = tmp[t] - v;  // exclusive
}

__global__ __launch_bounds__(256) void scan_final(const int* __restrict__ deg,
                                                  const int* __restrict__ psum,
                                                  int* __restrict__ rowptr, int n) {
    __shared__ int ts[256];
    int t = threadIdx.x;
    int base = blockIdx.x * SCAN_CHUNK + t * 4;
    int v[4];
    int s = 0;
    #pragma unroll
    for (int j = 0; j < 4; ++j) {
        int i = base + j;
        v[j] = (i < n) ? deg[i] : 0;
        s += v[j];
    }
    ts[t] = s;
    __syncthreads();
    int mine = s;
    for (int off = 1; off < 256; off <<= 1) {
        int u = (t >= off) ? ts[t - off] : 0;
        __syncthreads();
        ts[t] += u;
        __syncthreads();
    }
    int ex = ts[t] - mine + psum[blockIdx.x];
    #pragma unroll
    for (int j = 0; j < 4; ++j) {
        int i = base + j;
        if (i < n) rowptr[i] = ex;
        ex += v[j];
    }
}

__global__ __launch_bounds__(256) void node_arrays(const int* __restrict__ deg,
                                                   const int* __restrict__ rowptr,
                                                   float* __restrict__ ds,
                                                   int* __restrict__ cursor, int n) {
    int i = blockIdx.x * blockDim.x + threadIdx.x;
    if (i < n) {
        float d = (float)(deg[i] + 1);  // +1 self loop
        ds[i] = 1.0f / sqrtf(d);
        cursor[i] = rowptr[i];
    }
}

// Sharded CSR fill (R4 measured-best).
__global__ __launch_bounds__(256) void fill_csr_sharded(const int* __restrict__ src,
                                                        const int* __restrict__ dst,
                                                        int* __restrict__ cursor,
                                                        int* __restrict__ csr_src,
                                                        int E, int shard_w, int nchunks) {
    int shard = blockIdx.x & (FILL_S - 1);
    int chunk = blockIdx.x >> 3;
    int epc = (E + nchunks - 1) / nchunks;
    int e0 = chunk * epc;
    int e1 = min(e0 + epc, E);
    int lo = shard * shard_w, hi = lo + shard_w;
    for (int e = e0 + (int)threadIdx.x; e < e1; e += 256) {
        int d = dst[e];
        if (d >= lo && d < hi) {
            int pos = atomicAdd(&cursor[d], 1);
            csr_src[pos] = src[e];
        }
    }
}

// xp[n][16] = (j<14 ? x[n][j] : 0) * ds[n]
__global__ __launch_bounds__(256) void pad_scale_x(const float* __restrict__ x,
                                                   const float* __restrict__ ds,
                                                   float* __restrict__ xp, int n_nodes) {
    int idx = blockIdx.x * blockDim.x + threadIdx.x;
    if (idx >= n_nodes * 16) return;
    int n = idx >> 4, j = idx & 15;
    xp[idx] = (j < 14) ? x[n * 14 + j] * ds[n] : 0.0f;
}

// ---------------- layer-1 gather on 16-dim padded input (R7 exact) ----------------

__global__ __launch_bounds__(256) void gather16(const float* __restrict__ xp,
                                               const int* __restrict__ rowptr,
                                               const int* __restrict__ cnt,
                                               const int* __restrict__ csr_src,
                                               const float* __restrict__ ds,
                                               float* __restrict__ agg16, int n_nodes) {
    int lane = threadIdx.x & 63;
    int sub = lane >> 4, l = lane & 15;
    int wave = blockIdx.x * (blockDim.x >> 6) + (threadIdx.x >> 6);
    int node = wave * 4 + sub;
    if (node >= n_nodes) return;
    float dsn = ds[node];
    float a0 = xp[node * 16 + l];  // self
    float a1 = 0.f, a2 = 0.f, a3 = 0.f;
    int s = rowptr[node];
    int e = s + cnt[node];
    int i = s;
    for (; i + 3 < e; i += 4) {
        int s0 = csr_src[i], s1 = csr_src[i + 1], s2 = csr_src[i + 2], s3 = csr_src[i + 3];
        a0 += xp[s0 * 16 + l];
        a1 += xp[s1 * 16 + l];
        a2 += xp[s2 * 16 + l];
        a3 += xp[s3 * 16 + l];
    }
    for (; i < e; ++i) a0 += xp[csr_src[i] * 16 + l];
    agg16[node * 16 + l] = ((a0 + a1) + (a2 + a3)) * dsn;
}

// ---------------- dense GEMM: LDS-staged rows, bit-identical FMA order ----------------
// Wave per 4 nodes. Stage: one coalesced load (lane = float4 of the 4-row
// block) -> wave-private LDS slot (no barrier: same-wave write->read).
// Compute: the exact R7 loop body with r0..r3 pointing at LDS.

template <int K, int KW, bool BIAS_RELU, bool SCALE>
__global__ __launch_bounds__(256) void matmul_k(const float* __restrict__ h,
                                                const float* __restrict__ W,
                                                const float* __restrict__ bias,
                                                const float* __restrict__ ds,
                                                float* __restrict__ m, int n_nodes) {
    __shared__ float ldsbuf[4 * 4 * K];  // 4 waves x 4 rows x K
    int lane = threadIdx.x & 63;
    int wv = threadIdx.x >> 6;
    int wave = blockIdx.x * 4 + wv;
    int n0 = wave * 4;
    if (n0 >= n_nodes) return;
    float wcol[K];
    #pragma unroll
    for (int k = 0; k < K; ++k) wcol[k] = (k < KW) ? W[k * HDIM + lane] : 0.f;
    float bl = BIAS_RELU ? bias[lane] : 0.f;

    if (n0 + 3 < n_nodes) {
        float* myl = &ldsbuf[wv * 4 * K];
        const float4* src4 = reinterpret_cast<const float4*>(h + (size_t)n0 * K);
        if constexpr (K == 64) {
            reinterpret_cast<float4*>(myl)[lane] = src4[lane];   // 64 lanes = 64 float4 = 4 rows
        } else {
            if (lane < K) reinterpret_cast<float4*>(myl)[lane] = src4[lane];  // K float4s
        }
        // same-wave LDS write->read: in-order, compiler inserts lgkmcnt waits
        const float4* r0 = reinterpret_cast<const float4*>(myl + 0 * K);
        const float4* r1 = reinterpret_cast<const float4*>(myl + 1 * K);
        const float4* r2 = reinterpret_cast<const float4*>(myl + 2 * K);
        const float4* r3 = reinterpret_cast<const float4*>(myl + 3 * K);
        float a0[4] = {0, 0, 0, 0}, a1[4] = {0, 0, 0, 0};
        float a2[4] = {0, 0, 0, 0}, a3[4] = {0, 0, 0, 0};
        #pragma unroll
        for (int k4 = 0; k4 < K / 4; ++k4) {
            int c = k4 & 3;
            float4 v0 = r0[k4], v1 = r1[k4], v2 = r2[k4], v3 = r3[k4];
            float w0 = wcol[4 * k4 + 0], w1 = wcol[4 * k4 + 1];
            float w2 = wcol[4 * k4 + 2], w3 = wcol[4 * k4 + 3];
            a0[c] += v0.x * w0 + v0.y * w1 + v0.z * w2 + v0.w * w3;
            a1[c] += v1.x * w0 + v1.y * w1 + v1.z * w2 + v1.w * w3;
            a2[c] += v2.x * w0 + v2.y * w1 + v2.z * w2 + v2.w * w3;
            a3[c] += v3.x * w0 + v3.y * w1 + v3.z * w2 + v3.w * w3;
        }
        float s0 = (a0[0] + a0[1]) + (a0[2] + a0[3]);
        float s1 = (a1[0] + a1[1]) + (a1[2] + a1[3]);
        float s2 = (a2[0] + a2[1]) + (a2[2] + a2[3]);
        float s3 = (a3[0] + a3[1]) + (a3[2] + a3[3]);
        if constexpr (BIAS_RELU) {
            s0 = fmaxf(s0 + bl, 0.f);
            s1 = fmaxf(s1 + bl, 0.f);
            s2 = fmaxf(s2 + bl, 0.f);
            s3 = fmaxf(s3 + bl, 0.f);
        }
        if constexpr (SCALE) {
            s0 *= ds[n0 + 0];
            s1 *= ds[n0 + 1];
            s2 *= ds[n0 + 2];
            s3 *= ds[n0 + 3];
        }
        m[(size_t)(n0 + 0) * HDIM + lane] = s0;
        m[(size_t)(n0 + 1) * HDIM + lane] = s1;
        m[(size_t)(n0 + 2) * HDIM + lane] = s2;
        m[(size_t)(n0 + 3) * HDIM + lane] = s3;
    } else {
        for (int n = n0; n < n_nodes; ++n) {
            const float4* hrow = reinterpret_cast<const float4*>(h + (size_t)n * K);
            float acc[4] = {0, 0, 0, 0};
            #pragma unroll
            for (int k4 = 0; k4 < K / 4; ++k4) {
                float4 hv = hrow[k4];
                acc[k4 & 3] += hv.x * wcol[4 * k4 + 0] + hv.y * wcol[4 * k4 + 1] +
                               hv.z * wcol[4 * k4 + 2] + hv.w * wcol[4 * k4 + 3];
            }
            float s = (acc[0] + acc[1]) + (acc[2] + acc[3]);
            if constexpr (BIAS_RELU) s = fmaxf(s + bl, 0.f);
            if constexpr (SCALE) s *= ds[n];
            m[(size_t)n * HDIM + lane] = s;
        }
    }
}

// ---------------- CSR gather (layers 2-5): R7 exact, unroll x16 ----------------

__global__ __launch_bounds__(256) void gcn_gather(const float* __restrict__ m,
                                                  const int* __restrict__ rowptr,
                                                  const int* __restrict__ cnt,
                                                  const int* __restrict__ csr_src,
                                                  const float* __restrict__ ds,
                                                  const float* __restrict__ bias,
                                                  float* __restrict__ hout, int n_nodes) {
    int lane = threadIdx.x & 63;
    int node = blockIdx.x * (blockDim.x >> 6) + (threadIdx.x >> 6);
    if (node >= n_nodes) return;
    float dsn = ds[node];
    float a0 = m[node * HDIM + lane];  // self term (already ds-scaled)
    float a1 = 0.f, a2 = 0.f, a3 = 0.f;
    float a4 = 0.f, a5 = 0.f, a6 = 0.f, a7 = 0.f;
    int s = rowptr[node];
    int e = s + cnt[node];
    int i = s;
    for (; i + 15 < e; i += 16) {
        int t0 = csr_src[i],      t1 = csr_src[i + 1],  t2 = csr_src[i + 2],  t3 = csr_src[i + 3];
        int t4 = csr_src[i + 4],  t5 = csr_src[i + 5],  t6 = csr_src[i + 6],  t7 = csr_src[i + 7];
        int t8 = csr_src[i + 8],  t9 = csr_src[i + 9],  ta = csr_src[i + 10], tb = csr_src[i + 11];
        int tc = csr_src[i + 12], td = csr_src[i + 13], te = csr_src[i + 14], tf = csr_src[i + 15];
        a0 += m[t0 * HDIM + lane];
        a1 += m[t1 * HDIM + lane];
        a2 += m[t2 * HDIM + lane];
        a3 += m[t3 * HDIM + lane];
        a4 += m[t4 * HDIM + lane];
        a5 += m[t5 * HDIM + lane];
        a6 += m[t6 * HDIM + lane];
        a7 += m[t7 * HDIM + lane];
        a0 += m[t8 * HDIM + lane];
        a1 += m[t9 * HDIM + lane];
        a2 += m[ta * HDIM + lane];
        a3 += m[tb * HDIM + lane];
        a4 += m[tc * HDIM + lane];
        a5 += m[td * HDIM + lane];
        a6 += m[te * HDIM + lane];
        a7 += m[tf * HDIM + lane];
    }
    for (; i + 7 < e; i += 8) {
        int t0 = csr_src[i],     t1 = csr_src[i + 1], t2 = csr_src[i + 2], t3 = csr_src[i + 3];
        int t4 = csr_src[i + 4], t5 = csr_src[i + 5], t6 = csr_src[i + 6], t7 = csr_src[i + 7];
        a0 += m[t0 * HDIM + lane];
        a1 += m[t1 * HDIM + lane];
        a2 += m[t2 * HDIM + lane];
        a3 += m[t3 * HDIM + lane];
        a4 += m[t4 * HDIM + lane];
        a5 += m[t5 * HDIM + lane];
        a6 += m[t6 * HDIM + lane];
        a7 += m[t7 * HDIM + lane];
    }
    for (; i + 1 < e; i += 2) {
        int t0 = csr_src[i], t1 = csr_src[i + 1];
        a0 += m[t0 * HDIM + lane];
        a1 += m[t1 * HDIM + lane];
    }
    if (i < e) a0 += m[csr_src[i] * HDIM + lane];
    float v = ((a0 + a1) + (a2 + a3) + ((a4 + a5) + (a6 + a7))) * dsn + bias[lane];
    hout[node * HDIM + lane] = fmaxf(v, 0.f);
}

// ---------------- fused pool (segment max) + linear head (R7 exact) ----------------

__global__ __launch_bounds__(256) void pool_linear(const float* __restrict__ h,
                                                   const int* __restrict__ batch,
                                                   const float* __restrict__ Wlin,
                                                   const float* __restrict__ blin,
                                                   float* __restrict__ out,
                                                   int n_nodes, int n_graphs) {
    int lane = threadIdx.x & 63;
    int g = blockIdx.x * (blockDim.x >> 6) + (threadIdx.x >> 6);
    if (g >= n_graphs) return;
    int lo = 0, hi = n_nodes;
    while (lo < hi) { int mid = (lo + hi) >> 1; if (batch[mid] < g) lo = mid + 1; else hi = mid; }
    int start = lo;
    hi = n_nodes;
    while (lo < hi) { int mid = (lo + hi) >> 1; if (batch[mid] < g + 1) lo = mid + 1; else hi = mid; }
    int end = lo;
    float vmax = 0.f;  // h >= 0 post-relu
    for (int n = start; n < end; ++n) vmax = fmaxf(vmax, h[(size_t)n * HDIM + lane]);
    float p0 = vmax * Wlin[lane * 2 + 0];
    float p1 = vmax * Wlin[lane * 2 + 1];
    #pragma unroll
    for (int off = 32; off > 0; off >>= 1) {
        p0 += __shfl_xor(p0, off);
        p1 += __shfl_xor(p1, off);
    }
    if (lane == 0) {
        out[g * 2 + 0] = p0 + blin[0];
        out[g * 2 + 1] = p1 + blin[1];
    }
}

// ---------------- launch ----------------

extern "C" void kernel_launch(void* const* d_in, const int* in_sizes, int n_in,
                              void* d_out, int out_size, void* d_ws, size_t ws_size,
                              hipStream_t stream) {
    const float* x    = (const float*)d_in[0];
    const float* W1   = (const float*)d_in[1];
    const float* b1   = (const float*)d_in[2];
    const float* W2   = (const float*)d_in[3];
    const float* b2   = (const float*)d_in[4];
    const float* W3   = (const float*)d_in[5];
    const float* b3   = (const float*)d_in[6];
    const float* W4   = (const float*)d_in[7];
    const float* b4   = (const float*)d_in[8];
    const float* W5   = (const float*)d_in[9];
    const float* b5   = (const float*)d_in[10];
    const float* Wlin = (const float*)d_in[11];
    const float* blin = (const float*)d_in[12];
    const int* edge_index = (const int*)d_in[13];
    const int* batch      = (const int*)d_in[14];

    const int N = in_sizes[0] / 14;
    const int E = in_sizes[13] / 2;
    const int G = out_size / 2;
    const int* srcp = edge_index;
    const int* dstp = edge_index + E;

    char* ws = (char*)d_ws;
    size_t off = 0;
    auto alloc = [&](size_t bytes) -> void* {
        void* p = ws + off;
        off = (off + bytes + 255) & ~(size_t)255;
        return p;
    };
    int*   deg     = (int*)alloc((size_t)N * 4);
    int*   rowptr  = (int*)alloc((size_t)N * 4);
    int*   cursor  = (int*)alloc((size_t)N * 4);
    int*   psum    = (int*)alloc(128 * 4);
    float* ds      = (float*)alloc((size_t)N * 4);
    int*   csr_src = (int*)alloc((size_t)E * 4);
    float* buf_m   = (float*)alloc((size_t)N * HDIM * 4);
    float* buf_h   = (float*)alloc((size_t)N * HDIM * 4);
    (void)ws_size;
    // aliases (regions dead at time of use):
    float* xp    = buf_h;   // [N][16]
    float* agg16 = buf_m;   // [N][16]

    const int NB = (N + SCAN_CHUNK - 1) / SCAN_CHUNK;
    const int fill_chunks = 512;
    const int shard_w = (N + FILL_S - 1) / FILL_S;  // 12500

    hipMemsetAsync(deg, 0, (size_t)N * 4, stream);
    count_sharded<<<fill_chunks * FILL_S, 256, 0, stream>>>(dstp, deg, E, shard_w, fill_chunks);
    partial_sums<<<NB, 256, 0, stream>>>(deg, psum, N);
    scan_partials<<<1, 128, 0, stream>>>(psum, NB);
    scan_final<<<NB, 256, 0, stream>>>(deg, psum, rowptr, N);
    node_arrays<<<(N + 255) / 256, 256, 0, stream>>>(deg, rowptr, ds, cursor, N);
    pad_scale_x<<<(N * 16 + 255) / 256, 256, 0, stream>>>(x, ds, xp, N);
    fill_csr_sharded<<<fill_chunks * FILL_S, 256, 0, stream>>>(srcp, dstp, cursor, csr_src,
                                                               E, shard_w, fill_chunks);

    const int gemm_blocks = (N + 15) / 16;     // wave per 4 nodes
    const int gather_blocks = (N + 3) / 4;     // wave per node
    const int g16_blocks = (N + 15) / 16;

    // layer 1: agg16 = A_hat x (16-dim), then h1 = relu(agg16 @ W1 + b1)
    // (L1 SCALE=false — R7-proven scaling scheme)
    gather16<<<g16_blocks, 256, 0, stream>>>(xp, rowptr, deg, csr_src, ds, agg16, N);
    matmul_k<16, 14, true, false><<<gemm_blocks, 256, 0, stream>>>(agg16, W1, b1, ds, buf_h, N);

    // layers 2..5: m' = (h@W)*ds ; h = relu(ds*(sum m'[src] + m'[n]) + b)
    matmul_k<64, 64, false, true><<<gemm_blocks, 256, 0, stream>>>(buf_h, W2, b2, ds, buf_m, N);
    gcn_gather<<<gather_blocks, 256, 0, stream>>>(buf_m, rowptr, deg, csr_src, ds, b2, buf_h, N);
    matmul_k<64, 64, false, true><<<gemm_blocks, 256, 0, stream>>>(buf_h, W3, b3, ds, buf_m, N);
    gcn_gather<<<gather_blocks, 256, 0, stream>>>(buf_m, rowptr, deg, csr_src, ds, b3, buf_h, N);
    matmul_k<64, 64, false, true><<<gemm_blocks, 256, 0, stream>>>(buf_h, W4, b4, ds, buf_m, N);
    gcn_gather<<<gather_blocks, 256, 0, stream>>>(buf_m, rowptr, deg, csr_src, ds, b4, buf_h, N);
    matmul_k<64, 64, false, true><<<gemm_blocks, 256, 0, stream>>>(buf_h, W5, b5, ds, buf_m, N);
    gcn_gather<<<gather_blocks, 256, 0, stream>>>(buf_m, rowptr, deg, csr_src, ds, b5, buf_h, N);

    pool_linear<<<(G + 3) / 4, 256, 0, stream>>>(buf_h, batch, Wlin, blin, (float*)d_out, N, G);
}